// Round 3
// baseline (3050.892 us; speedup 1.0000x reference)
//
#include <hip/hip_runtime.h>

typedef unsigned short u16;
typedef unsigned int   u32;
typedef short bf16x8 __attribute__((ext_vector_type(8)));
typedef float f32x4  __attribute__((ext_vector_type(4)));

#define HID   512
#define NT    64            // columns per workgroup
#define NCOL  65536
#define PADC  520           // LDS column stride (elements)
#define MAT_ELEMS (512 * 512)
#define UB_ELEMS  (512 * 32)                 // per-gate [U|b|0..] block, swizzled
#define UB_OFF    (8 * MAT_ELEMS)            // u16 offset of ub blocks in ws
#define FLAG_OFF  (8 * MAT_ELEMS + 8 * UB_ELEMS)

__device__ __forceinline__ float bf2f(u16 v) {
  union { u32 u; float f; } t; t.u = ((u32)v) << 16; return t.f;
}
__device__ __forceinline__ u16 f2bf(float f) {
  union { float f; u32 u; } t; t.f = f;
  u32 r = t.u + 0x7fffu + ((t.u >> 16) & 1u);   // round-to-nearest-even
  return (u16)(r >> 16);
}
__device__ __forceinline__ float ldv(const void* p, int i, int isbf) {
  return isbf ? bf2f(((const u16*)p)[i]) : ((const float*)p)[i];
}
__device__ __forceinline__ float tanh_fast(float x) {
  float e = __builtin_amdgcn_exp2f(x * 2.8853900817779268f); // 2*log2(e)
  return 1.0f - 2.0f * __builtin_amdgcn_rcpf(e + 1.0f);
}

// ---------------- dtype sniff (parallel) ----------------
__global__ void sniff_kernel(const u16* x, u32* flag) {
  __shared__ int cnt[4];
  int i = threadIdx.x;                 // 256 threads
  u32 e = (x[i] >> 7) & 0xFFu;
  int ok = (e == 0u || (e >= 100u && e <= 140u)) ? 1 : 0;
  unsigned long long m = __ballot(ok);
  if ((i & 63) == 0) cnt[i >> 6] = __popcll(m);
  __syncthreads();
  if (i == 0) *flag = ((cnt[0] + cnt[1] + cnt[2] + cnt[3]) >= 220) ? 1u : 0u;
}

// ---------------- weight swizzle pre-pass ----------------
// Weight tile = kb*32 + rt, 512 bf16/tile, element (lane,j) at tile*512+lane*8+j,
// row = rt*16 + (lane&15), k = kb*32 + (lane>>4)*8 + j.
// ub block per gate: tile = rt (32 tiles), same lane layout, k' = (lane>>4)*8+j:
//   k'<3 -> U[row][k'], k'==3 -> bias[row], else 0.
struct SwzArgs {
  const void* src[8]; const void* u[8]; const void* bv[8];
  u16* dst; const u32* flag;
};

__global__ void swizzle_kernel(SwzArgs a) {
  const int isbf = (int)*a.flag;
  int bid = blockIdx.x;
  if (bid < 1024) {                      // weights: 262144 threads
    int t = bid * 256 + threadIdx.x;
    int m    = t >> 15;
    int rem  = t & 32767;
    int tile = rem >> 6;
    int lane = rem & 63;
    int kb = tile >> 5, rt = tile & 31;
    int row = rt * 16 + (lane & 15);
    int k   = kb * 32 + (lane >> 4) * 8;
    u16 tmp[8];
    if (isbf) {
      const u16* s = (const u16*)a.src[m] + row * 512 + k;
#pragma unroll
      for (int j = 0; j < 8; j++) tmp[j] = s[j];
    } else {
      const float* s = (const float*)a.src[m] + row * 512 + k;
#pragma unroll
      for (int j = 0; j < 8; j++) tmp[j] = f2bf(s[j]);
    }
    uint4* d = (uint4*)(a.dst + (size_t)m * MAT_ELEMS + (size_t)tile * 512 + lane * 8);
    *d = *(const uint4*)tmp;
  } else {                               // ub blocks: 16384 threads
    int t = (bid - 1024) * 256 + threadIdx.x;
    if (t >= 8 * 32 * 64) return;
    int g    = t >> 11;
    int rem  = t & 2047;
    int tile = rem >> 6;
    int lane = rem & 63;
    int row = tile * 16 + (lane & 15);
    int kq  = (lane >> 4) * 8;
    u16 tmp[8];
#pragma unroll
    for (int j = 0; j < 8; j++) {
      int k = kq + j;
      float v = (k < 3) ? ldv(a.u[g], row * 3 + k, isbf)
              : (k == 3) ? ldv(a.bv[g], row, isbf) : 0.0f;
      tmp[j] = f2bf(v);
    }
    uint4* d = (uint4*)(a.dst + UB_OFF + (size_t)g * UB_ELEMS + (size_t)tile * 512 + lane * 8);
    *d = *(const uint4*)tmp;
  }
}

// ---------------- fused network kernel ----------------
struct KArgs {
  const void* x;  const void* W1; const void* b1;
  const void* Wout; const void* bout;
  const u16* ws;      // swizzled weights + ub blocks (bf16)
  const u32* flag;
  void* out;
};

// Full gate GEMM: acc = [U|b]@[x;1] + W@S over K=512, M-slab 64 rows/wave, N=64.
__device__ __forceinline__ void gemm_full(f32x4 acc[4][4],
    const u16* __restrict__ wmat, const u16* __restrict__ ubm,
    const u16* ldsB, const u16* xbuf, int wave, int lane, int l15, int quad)
{
#pragma unroll
  for (int rt = 0; rt < 4; rt++)
#pragma unroll
    for (int ct = 0; ct < 4; ct++)
      acc[rt][ct] = (f32x4){0.f, 0.f, 0.f, 0.f};

  // ub block first: A = [U|b|0..], B = [x;1;0..] tile
  {
    const u16* aub = ubm + (wave * 4) * 512 + lane * 8;
    bf16x8 a[4], b[4];
#pragma unroll
    for (int i = 0; i < 4; i++) a[i] = *(const bf16x8*)(aub + i * 512);
#pragma unroll
    for (int i = 0; i < 4; i++) b[i] = *(const bf16x8*)(xbuf + (i * 16 + l15) * 32 + quad * 8);
#pragma unroll
    for (int rt = 0; rt < 4; rt++)
#pragma unroll
      for (int ct = 0; ct < 4; ct++)
        acc[rt][ct] = __builtin_amdgcn_mfma_f32_16x16x32_bf16(a[rt], b[ct], acc[rt][ct], 0, 0, 0);
  }
  const u16* abase = wmat + (size_t)(wave * 4) * 512 + lane * 8;
  const u16* bbase = ldsB + l15 * PADC + quad * 8;
#pragma unroll
  for (int kb = 0; kb < 16; kb++) {
    bf16x8 a[4], b[4];
#pragma unroll
    for (int i = 0; i < 4; i++)
      a[i] = *(const bf16x8*)(abase + (size_t)kb * 32 * 512 + i * 512);
#pragma unroll
    for (int i = 0; i < 4; i++)
      b[i] = *(const bf16x8*)(bbase + kb * 32 + i * 16 * PADC);
#pragma unroll
    for (int rt = 0; rt < 4; rt++)
#pragma unroll
      for (int ct = 0; ct < 4; ct++)
        acc[rt][ct] = __builtin_amdgcn_mfma_f32_16x16x32_bf16(a[rt], b[ct], acc[rt][ct], 0, 0, 0);
  }
}

__global__ __launch_bounds__(512, 4) void pdenet_kernel(KArgs ka) {
  __shared__ __align__(16) u16 ldsB[NT * PADC];   // S, then SR in place, then S_next
  __shared__ __align__(16) u16 xbuf[NT * 32];     // [x;1;0..] K=32 tile, col-major

  const int isbf = (int)*ka.flag;
  const int tid  = threadIdx.x;
  const int wave = tid >> 6;
  const int lane = tid & 63;
  const int l15  = lane & 15;
  const int quad = lane >> 4;
  const int c0   = blockIdx.x * NT;

  // build xbuf once
  for (int e = tid; e < NT * 32; e += 512) {
    int cc = e >> 5, k = e & 31;
    float v = (k < 3) ? ldv(ka.x, k * NCOL + c0 + cc, isbf)
            : (k == 3) ? 1.0f : 0.0f;
    xbuf[cc * 32 + k] = f2bf(v);
  }
  __syncthreads();

  // S1 = tanh(W1@x + b1): thread = row
  {
    int r = tid;
    float w0 = ldv(ka.W1, r * 3 + 0, isbf);
    float w1 = ldv(ka.W1, r * 3 + 1, isbf);
    float w2 = ldv(ka.W1, r * 3 + 2, isbf);
    float bb = ldv(ka.b1, r, isbf);
#pragma unroll 4
    for (int c = 0; c < NT; c++) {
      float x0 = bf2f(xbuf[c * 32 + 0]);
      float x1 = bf2f(xbuf[c * 32 + 1]);
      float x2 = bf2f(xbuf[c * 32 + 2]);
      float s = tanh_fast(w0 * x0 + w1 * x1 + w2 * x2 + bb);
      ldsB[c * PADC + r] = f2bf(s);
    }
  }
  __syncthreads();

  u32 zpk[4][4][2], gpk[4][4][2], spk[4][4][2];  // packed bf16 pairs in regs

#pragma unroll
  for (int layer = 0; layer < 2; layer++) {
    const int g0 = layer * 4;
    const u16* wbase  = ka.ws;
    const u16* ubbase = ka.ws + UB_OFF;

    // ---- Z ----
    {
      f32x4 acc[4][4];
      gemm_full(acc, wbase + (size_t)(g0 + 0) * MAT_ELEMS, ubbase + (size_t)(g0 + 0) * UB_ELEMS,
                ldsB, xbuf, wave, lane, l15, quad);
#pragma unroll
      for (int rt = 0; rt < 4; rt++)
#pragma unroll
        for (int ct = 0; ct < 4; ct++) {
          u16 t0 = f2bf(tanh_fast(acc[rt][ct][0]));
          u16 t1 = f2bf(tanh_fast(acc[rt][ct][1]));
          u16 t2 = f2bf(tanh_fast(acc[rt][ct][2]));
          u16 t3 = f2bf(tanh_fast(acc[rt][ct][3]));
          zpk[rt][ct][0] = (u32)t0 | ((u32)t1 << 16);
          zpk[rt][ct][1] = (u32)t2 | ((u32)t3 << 16);
        }
    }
    // ---- G ----
    {
      f32x4 acc[4][4];
      gemm_full(acc, wbase + (size_t)(g0 + 1) * MAT_ELEMS, ubbase + (size_t)(g0 + 1) * UB_ELEMS,
                ldsB, xbuf, wave, lane, l15, quad);
#pragma unroll
      for (int rt = 0; rt < 4; rt++)
#pragma unroll
        for (int ct = 0; ct < 4; ct++) {
          u16 t0 = f2bf(tanh_fast(acc[rt][ct][0]));
          u16 t1 = f2bf(tanh_fast(acc[rt][ct][1]));
          u16 t2 = f2bf(tanh_fast(acc[rt][ct][2]));
          u16 t3 = f2bf(tanh_fast(acc[rt][ct][3]));
          gpk[rt][ct][0] = (u32)t0 | ((u32)t1 << 16);
          gpk[rt][ct][1] = (u32)t2 | ((u32)t3 << 16);
        }
    }
    // ---- R ----
    f32x4 racc[4][4];
    gemm_full(racc, wbase + (size_t)(g0 + 2) * MAT_ELEMS, ubbase + (size_t)(g0 + 2) * UB_ELEMS,
              ldsB, xbuf, wave, lane, l15, quad);
    __syncthreads();   // all waves done reading S as B operand
    // epilogue: cache own S in regs, overwrite with SR = S * tanh(R)
#pragma unroll
    for (int rt = 0; rt < 4; rt++)
#pragma unroll
      for (int ct = 0; ct < 4; ct++) {
        int c  = ct * 16 + l15;
        int rb = wave * 64 + rt * 16 + quad * 4;
        u16* p = &ldsB[c * PADC + rb];
        uint2 sv = *(const uint2*)p;
        spk[rt][ct][0] = sv.x;
        spk[rt][ct][1] = sv.y;
        float s0 = bf2f((u16)(sv.x & 0xffffu)), s1 = bf2f((u16)(sv.x >> 16));
        float s2 = bf2f((u16)(sv.y & 0xffffu)), s3 = bf2f((u16)(sv.y >> 16));
        u16 o0 = f2bf(s0 * tanh_fast(racc[rt][ct][0]));
        u16 o1 = f2bf(s1 * tanh_fast(racc[rt][ct][1]));
        u16 o2 = f2bf(s2 * tanh_fast(racc[rt][ct][2]));
        u16 o3 = f2bf(s3 * tanh_fast(racc[rt][ct][3]));
        uint2 ov = { (u32)o0 | ((u32)o1 << 16), (u32)o2 | ((u32)o3 << 16) };
        *(uint2*)p = ov;
      }
    __syncthreads();   // SR published
    // ---- H; S_next = (1-G)*H + Z*S ----
    {
      f32x4 acc[4][4];
      gemm_full(acc, wbase + (size_t)(g0 + 3) * MAT_ELEMS, ubbase + (size_t)(g0 + 3) * UB_ELEMS,
                ldsB, xbuf, wave, lane, l15, quad);
      __syncthreads(); // all waves done reading SR
#pragma unroll
      for (int rt = 0; rt < 4; rt++)
#pragma unroll
        for (int ct = 0; ct < 4; ct++) {
          int c  = ct * 16 + l15;
          int rb = wave * 64 + rt * 16 + quad * 4;
          u16 o[4];
#pragma unroll
          for (int i = 0; i < 4; i++) {
            float h = tanh_fast(acc[rt][ct][i]);
            u32 zp = zpk[rt][ct][i >> 1], gp = gpk[rt][ct][i >> 1], sp = spk[rt][ct][i >> 1];
            float z = bf2f((u16)((i & 1) ? (zp >> 16) : (zp & 0xffffu)));
            float g = bf2f((u16)((i & 1) ? (gp >> 16) : (gp & 0xffffu)));
            float s = bf2f((u16)((i & 1) ? (sp >> 16) : (sp & 0xffffu)));
            o[i] = f2bf((1.0f - g) * h + z * s);
          }
          uint2 ov = { (u32)o[0] | ((u32)o[1] << 16), (u32)o[2] | ((u32)o[3] << 16) };
          *(uint2*)&ldsB[c * PADC + rb] = ov;
        }
    }
    __syncthreads();   // S_next published
  }

  // ---- out = W @ S3 + b : 8 threads/col, seg is the fast 16B chunk dim ----
  {
    int c = tid >> 3;
    int seg = tid & 7;
    float p = 0.0f;
#pragma unroll
    for (int t = 0; t < 8; t++) {
      int rbase = t * 64 + seg * 8;
      bf16x8 s8 = *(const bf16x8*)&ldsB[c * PADC + rbase];
#pragma unroll
      for (int j = 0; j < 8; j++)
        p += ldv(ka.Wout, rbase + j, isbf) * bf2f((u16)s8[j]);
    }
    p += __shfl_xor(p, 1);
    p += __shfl_xor(p, 2);
    p += __shfl_xor(p, 4);
    if (seg == 0) {
      float res = p + ldv(ka.bout, 0, isbf);
      if (isbf) ((u16*)ka.out)[c0 + c] = f2bf(res);
      else      ((float*)ka.out)[c0 + c] = res;
    }
  }
}

extern "C" void kernel_launch(void* const* d_in, const int* in_sizes, int n_in,
                              void* d_out, int out_size, void* d_ws, size_t ws_size,
                              hipStream_t stream) {
  // 0:x 1:W1 2:b1 | 3:Uz1 4:Wz1 5:bz1 | 6:Ug1 7:Wg1 8:bg1 | 9:Ur1 10:Wr1 11:br1
  // 12:Uh1 13:Wh1 14:bh1 | 15:Uz2 16:Wz2 17:bz2 | 18:Ug2 19:Wg2 20:bg2
  // 21:Ur2 22:Wr2 23:br2 | 24:Uh2 25:Wh2 26:bh2 | 27:W 28:b
  static const int widx[8] = {4, 7, 10, 13, 16, 19, 22, 25};
  static const int uidx[8] = {3, 6, 9, 12, 15, 18, 21, 24};
  static const int bidx[8] = {5, 8, 11, 14, 17, 20, 23, 26};

  u16* ws16  = (u16*)d_ws;
  u32* flagp = (u32*)(ws16 + FLAG_OFF);

  hipLaunchKernelGGL(sniff_kernel, dim3(1), dim3(256), 0, stream,
                     (const u16*)d_in[0], flagp);

  SwzArgs sa;
  for (int i = 0; i < 8; i++) {
    sa.src[i] = d_in[widx[i]];
    sa.u[i]   = d_in[uidx[i]];
    sa.bv[i]  = d_in[bidx[i]];
  }
  sa.dst  = ws16;
  sa.flag = flagp;
  hipLaunchKernelGGL(swizzle_kernel, dim3(1024 + 64), dim3(256), 0, stream, sa);

  KArgs ka;
  ka.x    = d_in[0];
  ka.W1   = d_in[1];
  ka.b1   = d_in[2];
  ka.Wout = d_in[27];
  ka.bout = d_in[28];
  ka.ws   = ws16;
  ka.flag = flagp;
  ka.out  = d_out;
  hipLaunchKernelGGL(pdenet_kernel, dim3(NCOL / NT), dim3(512), 0, stream, ka);
}

// Round 4
// 941.213 us; speedup vs baseline: 3.2414x; 3.2414x over previous
//
#include <hip/hip_runtime.h>

typedef unsigned short u16;
typedef unsigned int   u32;
typedef short bf16x8 __attribute__((ext_vector_type(8)));
typedef float f32x4  __attribute__((ext_vector_type(4)));

#define HID   512
#define NT    64            // columns per workgroup
#define NCOL  65536
#define PADC  520           // LDS column stride (elements)
#define MAT_ELEMS (512 * 512)
#define UB_ELEMS  (512 * 32)                 // per-gate [U|b|0..] block, swizzled
#define UB_OFF    (8 * MAT_ELEMS)            // u16 offset of ub blocks in ws

__device__ __forceinline__ float bf2f(u16 v) {
  union { u32 u; float f; } t; t.u = ((u32)v) << 16; return t.f;
}
__device__ __forceinline__ u16 f2bf(float f) {
  union { float f; u32 u; } t; t.f = f;
  u32 r = t.u + 0x7fffu + ((t.u >> 16) & 1u);   // round-to-nearest-even
  return (u16)(r >> 16);
}
__device__ __forceinline__ float ldv(const void* p, int i, int isbf) {
  return isbf ? bf2f(((const u16*)p)[i]) : ((const float*)p)[i];
}
__device__ __forceinline__ float tanh_fast(float x) {
  float e = __builtin_amdgcn_exp2f(x * 2.8853900817779268f); // 2*log2(e)
  return 1.0f - 2.0f * __builtin_amdgcn_rcpf(e + 1.0f);
}

// block-uniform dtype sniff: first 256 threads inspect x's first 256 u16s.
// bf16 data -> ~all plausible exponents; fp32 -> only high halves (~58%).
__device__ __forceinline__ int sniff_isbf(const void* x, int tid, int* scnt) {
  if (tid < 256) {
    u32 e = (((const u16*)x)[tid] >> 7) & 0xFFu;
    int ok = (e == 0u || (e - 100u) <= 40u) ? 1 : 0;
    unsigned long long m = __ballot(ok);
    if ((tid & 63) == 0) scnt[tid >> 6] = __popcll(m);
  }
  __syncthreads();
  return ((scnt[0] + scnt[1] + scnt[2] + scnt[3]) >= 220) ? 1 : 0;
}

// ---------------- weight swizzle pre-pass ----------------
// Weight tile = kb*32 + rt, 512 bf16/tile, element (lane,j) at tile*512+lane*8+j,
// row = rt*16 + (lane&15), k = kb*32 + (lane>>4)*8 + j.
// ub block per gate: tile = rt (32 tiles), same lane layout, k' = (lane>>4)*8+j:
//   k'<3 -> U[row][k'], k'==3 -> bias[row], else 0.
struct SwzArgs {
  const void* src[8]; const void* u[8]; const void* bv[8];
  const void* x; u16* dst;
};

__global__ void swizzle_kernel(SwzArgs a) {
  __shared__ int scnt[4];
  const int isbf = sniff_isbf(a.x, threadIdx.x, scnt);
  int bid = blockIdx.x;
  if (bid < 1024) {                      // weights: 262144 threads
    int t = bid * 256 + threadIdx.x;
    int m    = t >> 15;
    int rem  = t & 32767;
    int tile = rem >> 6;
    int lane = rem & 63;
    int kb = tile >> 5, rt = tile & 31;
    int row = rt * 16 + (lane & 15);
    int k   = kb * 32 + (lane >> 4) * 8;
    u16 tmp[8];
    if (isbf) {
      const u16* s = (const u16*)a.src[m] + row * 512 + k;
#pragma unroll
      for (int j = 0; j < 8; j++) tmp[j] = s[j];
    } else {
      const float* s = (const float*)a.src[m] + row * 512 + k;
#pragma unroll
      for (int j = 0; j < 8; j++) tmp[j] = f2bf(s[j]);
    }
    uint4* d = (uint4*)(a.dst + (size_t)m * MAT_ELEMS + (size_t)tile * 512 + lane * 8);
    *d = *(const uint4*)tmp;
  } else {                               // ub blocks: 16384 threads
    int t = (bid - 1024) * 256 + threadIdx.x;
    if (t >= 8 * 32 * 64) return;
    int g    = t >> 11;
    int rem  = t & 2047;
    int tile = rem >> 6;
    int lane = rem & 63;
    int row = tile * 16 + (lane & 15);
    int kq  = (lane >> 4) * 8;
    u16 tmp[8];
#pragma unroll
    for (int j = 0; j < 8; j++) {
      int k = kq + j;
      float v = (k < 3) ? ldv(a.u[g], row * 3 + k, isbf)
              : (k == 3) ? ldv(a.bv[g], row, isbf) : 0.0f;
      tmp[j] = f2bf(v);
    }
    uint4* d = (uint4*)(a.dst + UB_OFF + (size_t)g * UB_ELEMS + (size_t)tile * 512 + lane * 8);
    *d = *(const uint4*)tmp;
  }
}

// ---------------- fused network kernel ----------------
struct KArgs {
  const void* x;  const void* W1; const void* b1;
  const void* Wout; const void* bout;
  const u16* ws;      // swizzled weights + ub blocks (bf16)
  void* out;
};

// Single-gate GEMM: acc = [U|b]@[x;1] + W@B over K=512, 64 rows/wave, N=64.
__device__ __forceinline__ void gemm_one(f32x4 acc[4][4],
    const u16* __restrict__ wmat, const u16* __restrict__ ubm,
    const u16* ldsB, const u16* xbuf, int wave, int lane, int l15, int quad)
{
#pragma unroll
  for (int rt = 0; rt < 4; rt++)
#pragma unroll
    for (int ct = 0; ct < 4; ct++)
      acc[rt][ct] = (f32x4){0.f, 0.f, 0.f, 0.f};
  {
    const u16* aub = ubm + (wave * 4) * 512 + lane * 8;
    bf16x8 a[4], b[4];
#pragma unroll
    for (int i = 0; i < 4; i++) a[i] = *(const bf16x8*)(aub + i * 512);
#pragma unroll
    for (int i = 0; i < 4; i++) b[i] = *(const bf16x8*)(xbuf + (i * 16 + l15) * 32 + quad * 8);
#pragma unroll
    for (int rt = 0; rt < 4; rt++)
#pragma unroll
      for (int ct = 0; ct < 4; ct++)
        acc[rt][ct] = __builtin_amdgcn_mfma_f32_16x16x32_bf16(a[rt], b[ct], acc[rt][ct], 0, 0, 0);
  }
  const u16* abase = wmat + (size_t)(wave * 4) * 512 + lane * 8;
  const u16* bbase = ldsB + l15 * PADC + quad * 8;
#pragma unroll
  for (int kb = 0; kb < 16; kb++) {
    bf16x8 a[4], b[4];
#pragma unroll
    for (int i = 0; i < 4; i++)
      a[i] = *(const bf16x8*)(abase + (size_t)kb * 16384 + i * 512);
#pragma unroll
    for (int i = 0; i < 4; i++)
      b[i] = *(const bf16x8*)(bbase + kb * 32 + i * 16 * PADC);
#pragma unroll
    for (int rt = 0; rt < 4; rt++)
#pragma unroll
      for (int ct = 0; ct < 4; ct++)
        acc[rt][ct] = __builtin_amdgcn_mfma_f32_16x16x32_bf16(a[rt], b[ct], acc[rt][ct], 0, 0, 0);
  }
}

__device__ __forceinline__ void pack_tanh(u32 dst[4][4][2], const f32x4 acc[4][4]) {
#pragma unroll
  for (int rt = 0; rt < 4; rt++)
#pragma unroll
    for (int ct = 0; ct < 4; ct++) {
      u16 t0 = f2bf(tanh_fast(acc[rt][ct][0]));
      u16 t1 = f2bf(tanh_fast(acc[rt][ct][1]));
      u16 t2 = f2bf(tanh_fast(acc[rt][ct][2]));
      u16 t3 = f2bf(tanh_fast(acc[rt][ct][3]));
      dst[rt][ct][0] = (u32)t0 | ((u32)t1 << 16);
      dst[rt][ct][1] = (u32)t2 | ((u32)t3 << 16);
    }
}

__global__ __launch_bounds__(512, 2) void pdenet_kernel(KArgs ka) {
  __shared__ __align__(16) u16 ldsS[NT * PADC];   // S (stays intact within a layer)
  __shared__ __align__(16) u16 ldsR[NT * PADC];   // SR buffer
  __shared__ __align__(16) u16 xbuf[NT * 32];     // [x;1;0..] K=32 tile, col-major
  __shared__ int scnt[4];

  const int tid  = threadIdx.x;
  const int isbf = sniff_isbf(ka.x, tid, scnt);
  const int wave = tid >> 6;
  const int lane = tid & 63;
  const int l15  = lane & 15;
  const int quad = lane >> 4;
  const int c0   = blockIdx.x * NT;

  // build xbuf once
  for (int e = tid; e < NT * 32; e += 512) {
    int cc = e >> 5, k = e & 31;
    float v = (k < 3) ? ldv(ka.x, k * NCOL + c0 + cc, isbf)
            : (k == 3) ? 1.0f : 0.0f;
    xbuf[cc * 32 + k] = f2bf(v);
  }
  __syncthreads();

  // S1 = tanh(W1@x + b1): thread = row
  {
    int r = tid;
    float w0 = ldv(ka.W1, r * 3 + 0, isbf);
    float w1 = ldv(ka.W1, r * 3 + 1, isbf);
    float w2 = ldv(ka.W1, r * 3 + 2, isbf);
    float bb = ldv(ka.b1, r, isbf);
#pragma unroll 4
    for (int c = 0; c < NT; c++) {
      float x0 = bf2f(xbuf[c * 32 + 0]);
      float x1 = bf2f(xbuf[c * 32 + 1]);
      float x2 = bf2f(xbuf[c * 32 + 2]);
      float s = tanh_fast(w0 * x0 + w1 * x1 + w2 * x2 + bb);
      ldsS[c * PADC + r] = f2bf(s);
    }
  }
  __syncthreads();

  u32 zpk[4][4][2], gpk[4][4][2];

#pragma unroll 1
  for (int layer = 0; layer < 2; layer++) {
    const int g0 = layer * 4;
    const u16* ubb = ka.ws + UB_OFF;

    // ---- Z + G fused K-loop (shared B fragments from ldsS) ----
    {
      f32x4 az[4][4], ag[4][4];
#pragma unroll
      for (int rt = 0; rt < 4; rt++)
#pragma unroll
        for (int ct = 0; ct < 4; ct++) {
          az[rt][ct] = (f32x4){0.f, 0.f, 0.f, 0.f};
          ag[rt][ct] = (f32x4){0.f, 0.f, 0.f, 0.f};
        }
      {  // ub step: B = xbuf
        const u16* ubz = ubb + (size_t)(g0 + 0) * UB_ELEMS + (wave * 4) * 512 + lane * 8;
        const u16* ubg = ubb + (size_t)(g0 + 1) * UB_ELEMS + (wave * 4) * 512 + lane * 8;
        bf16x8 a0[4], a1[4], b[4];
#pragma unroll
        for (int i = 0; i < 4; i++) {
          a0[i] = *(const bf16x8*)(ubz + i * 512);
          a1[i] = *(const bf16x8*)(ubg + i * 512);
          b[i]  = *(const bf16x8*)(xbuf + (i * 16 + l15) * 32 + quad * 8);
        }
#pragma unroll
        for (int rt = 0; rt < 4; rt++)
#pragma unroll
          for (int ct = 0; ct < 4; ct++) {
            az[rt][ct] = __builtin_amdgcn_mfma_f32_16x16x32_bf16(a0[rt], b[ct], az[rt][ct], 0, 0, 0);
            ag[rt][ct] = __builtin_amdgcn_mfma_f32_16x16x32_bf16(a1[rt], b[ct], ag[rt][ct], 0, 0, 0);
          }
      }
      const u16* wz = ka.ws + (size_t)(g0 + 0) * MAT_ELEMS + (wave * 4) * 512 + lane * 8;
      const u16* wg = ka.ws + (size_t)(g0 + 1) * MAT_ELEMS + (wave * 4) * 512 + lane * 8;
      const u16* bbase = ldsS + l15 * PADC + quad * 8;
#pragma unroll
      for (int kb = 0; kb < 16; kb++) {
        bf16x8 a0[4], a1[4], b[4];
#pragma unroll
        for (int i = 0; i < 4; i++) {
          a0[i] = *(const bf16x8*)(wz + (size_t)kb * 16384 + i * 512);
          a1[i] = *(const bf16x8*)(wg + (size_t)kb * 16384 + i * 512);
          b[i]  = *(const bf16x8*)(bbase + kb * 32 + i * 16 * PADC);
        }
#pragma unroll
        for (int rt = 0; rt < 4; rt++)
#pragma unroll
          for (int ct = 0; ct < 4; ct++) {
            az[rt][ct] = __builtin_amdgcn_mfma_f32_16x16x32_bf16(a0[rt], b[ct], az[rt][ct], 0, 0, 0);
            ag[rt][ct] = __builtin_amdgcn_mfma_f32_16x16x32_bf16(a1[rt], b[ct], ag[rt][ct], 0, 0, 0);
          }
      }
      pack_tanh(zpk, az);
      pack_tanh(gpk, ag);
    }

    // ---- R; SR = S * tanh(R) -> ldsR ----
    {
      f32x4 racc[4][4];
      gemm_one(racc, ka.ws + (size_t)(g0 + 2) * MAT_ELEMS,
               ubb + (size_t)(g0 + 2) * UB_ELEMS, ldsS, xbuf, wave, lane, l15, quad);
#pragma unroll
      for (int rt = 0; rt < 4; rt++)
#pragma unroll
        for (int ct = 0; ct < 4; ct++) {
          int c  = ct * 16 + l15;
          int rb = wave * 64 + rt * 16 + quad * 4;
          uint2 sv = *(const uint2*)&ldsS[c * PADC + rb];
          float s0 = bf2f((u16)(sv.x & 0xffffu)), s1 = bf2f((u16)(sv.x >> 16));
          float s2 = bf2f((u16)(sv.y & 0xffffu)), s3 = bf2f((u16)(sv.y >> 16));
          u16 o0 = f2bf(s0 * tanh_fast(racc[rt][ct][0]));
          u16 o1 = f2bf(s1 * tanh_fast(racc[rt][ct][1]));
          u16 o2 = f2bf(s2 * tanh_fast(racc[rt][ct][2]));
          u16 o3 = f2bf(s3 * tanh_fast(racc[rt][ct][3]));
          uint2 ov = { (u32)o0 | ((u32)o1 << 16), (u32)o2 | ((u32)o3 << 16) };
          *(uint2*)&ldsR[c * PADC + rb] = ov;
        }
    }
    __syncthreads();   // SR published

    // ---- H (B = ldsR); S_next = (1-G)*H + Z*S -> ldsS (own rows only) ----
    {
      f32x4 acc[4][4];
      gemm_one(acc, ka.ws + (size_t)(g0 + 3) * MAT_ELEMS,
               ubb + (size_t)(g0 + 3) * UB_ELEMS, ldsR, xbuf, wave, lane, l15, quad);
#pragma unroll
      for (int rt = 0; rt < 4; rt++)
#pragma unroll
        for (int ct = 0; ct < 4; ct++) {
          int c  = ct * 16 + l15;
          int rb = wave * 64 + rt * 16 + quad * 4;
          uint2 sv = *(const uint2*)&ldsS[c * PADC + rb];
          u16 o[4];
#pragma unroll
          for (int i = 0; i < 4; i++) {
            float h = tanh_fast(acc[rt][ct][i]);
            u32 zp = zpk[rt][ct][i >> 1], gp = gpk[rt][ct][i >> 1];
            u32 sp = (i >> 1) ? sv.y : sv.x;
            float z = bf2f((u16)((i & 1) ? (zp >> 16) : (zp & 0xffffu)));
            float g = bf2f((u16)((i & 1) ? (gp >> 16) : (gp & 0xffffu)));
            float s = bf2f((u16)((i & 1) ? (sp >> 16) : (sp & 0xffffu)));
            o[i] = f2bf((1.0f - g) * h + z * s);
          }
          uint2 ov = { (u32)o[0] | ((u32)o[1] << 16), (u32)o[2] | ((u32)o[3] << 16) };
          *(uint2*)&ldsS[c * PADC + rb] = ov;
        }
    }
    __syncthreads();   // S_next published
  }

  // ---- out = W @ S3 + b : 8 threads/col ----
  {
    int c = tid >> 3;
    int seg = tid & 7;
    float p = 0.0f;
#pragma unroll
    for (int t = 0; t < 8; t++) {
      int rbase = t * 64 + seg * 8;
      bf16x8 s8 = *(const bf16x8*)&ldsS[c * PADC + rbase];
#pragma unroll
      for (int j = 0; j < 8; j++)
        p += ldv(ka.Wout, rbase + j, isbf) * bf2f((u16)s8[j]);
    }
    p += __shfl_xor(p, 1);
    p += __shfl_xor(p, 2);
    p += __shfl_xor(p, 4);
    if (seg == 0) {
      float res = p + ldv(ka.bout, 0, isbf);
      if (isbf) ((u16*)ka.out)[c0 + c] = f2bf(res);
      else      ((float*)ka.out)[c0 + c] = res;
    }
  }
}

extern "C" void kernel_launch(void* const* d_in, const int* in_sizes, int n_in,
                              void* d_out, int out_size, void* d_ws, size_t ws_size,
                              hipStream_t stream) {
  // 0:x 1:W1 2:b1 | 3:Uz1 4:Wz1 5:bz1 | 6:Ug1 7:Wg1 8:bg1 | 9:Ur1 10:Wr1 11:br1
  // 12:Uh1 13:Wh1 14:bh1 | 15:Uz2 16:Wz2 17:bz2 | 18:Ug2 19:Wg2 20:bg2
  // 21:Ur2 22:Wr2 23:br2 | 24:Uh2 25:Wh2 26:bh2 | 27:W 28:b
  static const int widx[8] = {4, 7, 10, 13, 16, 19, 22, 25};
  static const int uidx[8] = {3, 6, 9, 12, 15, 18, 21, 24};
  static const int bidx[8] = {5, 8, 11, 14, 17, 20, 23, 26};

  u16* ws16 = (u16*)d_ws;

  SwzArgs sa;
  for (int i = 0; i < 8; i++) {
    sa.src[i] = d_in[widx[i]];
    sa.u[i]   = d_in[uidx[i]];
    sa.bv[i]  = d_in[bidx[i]];
  }
  sa.x   = d_in[0];
  sa.dst = ws16;
  hipLaunchKernelGGL(swizzle_kernel, dim3(1024 + 64), dim3(256), 0, stream, sa);

  KArgs ka;
  ka.x    = d_in[0];
  ka.W1   = d_in[1];
  ka.b1   = d_in[2];
  ka.Wout = d_in[27];
  ka.bout = d_in[28];
  ka.ws   = ws16;
  ka.out  = d_out;
  hipLaunchKernelGGL(pdenet_kernel, dim3(NCOL / NT), dim3(512), 0, stream, ka);
}

// Round 5
// 931.224 us; speedup vs baseline: 3.2762x; 1.0107x over previous
//
#include <hip/hip_runtime.h>

typedef unsigned short u16;
typedef unsigned int   u32;
typedef short bf16x8 __attribute__((ext_vector_type(8)));
typedef float f32x4  __attribute__((ext_vector_type(4)));

#define HID   512
#define NT    64            // columns per workgroup
#define NCOL  65536
#define PADC  520           // LDS column stride (elements)
#define MAT_ELEMS (512 * 512)
#define UB_ELEMS  (512 * 32)                 // per-gate [U|b|0..] block, swizzled
#define UB_OFF    (8 * MAT_ELEMS)            // u16 offset of ub blocks in ws

__device__ __forceinline__ float bf2f(u16 v) {
  union { u32 u; float f; } t; t.u = ((u32)v) << 16; return t.f;
}
__device__ __forceinline__ u16 f2bf(float f) {
  union { float f; u32 u; } t; t.f = f;
  u32 r = t.u + 0x7fffu + ((t.u >> 16) & 1u);   // round-to-nearest-even
  return (u16)(r >> 16);
}
__device__ __forceinline__ float ldv(const void* p, int i, int isbf) {
  return isbf ? bf2f(((const u16*)p)[i]) : ((const float*)p)[i];
}
__device__ __forceinline__ float tanh_fast(float x) {
  float e = __builtin_amdgcn_exp2f(x * 2.8853900817779268f); // 2*log2(e)
  return 1.0f - 2.0f * __builtin_amdgcn_rcpf(e + 1.0f);
}

// block-uniform dtype sniff: first 256 threads inspect x's first 256 u16s.
__device__ __forceinline__ int sniff_isbf(const void* x, int tid, int* scnt) {
  if (tid < 256) {
    u32 e = (((const u16*)x)[tid] >> 7) & 0xFFu;
    int ok = (e == 0u || (e - 100u) <= 40u) ? 1 : 0;
    unsigned long long m = __ballot(ok);
    if ((tid & 63) == 0) scnt[tid >> 6] = __popcll(m);
  }
  __syncthreads();
  return ((scnt[0] + scnt[1] + scnt[2] + scnt[3]) >= 220) ? 1 : 0;
}

// ---------------- weight swizzle pre-pass ----------------
// Weight tile = kb*32 + rt, 512 bf16/tile, element (lane,j) at tile*512+lane*8+j,
// row = rt*16 + (lane&15), k = kb*32 + (lane>>4)*8 + j.
// ub block per gate: tile = rt (32 tiles), same lane layout, k' = (lane>>4)*8+j:
//   k'<3 -> U[row][k'], k'==3 -> bias[row], else 0.
struct SwzArgs {
  const void* src[8]; const void* u[8]; const void* bv[8];
  const void* x; u16* dst;
};

__global__ void swizzle_kernel(SwzArgs a) {
  __shared__ int scnt[4];
  const int isbf = sniff_isbf(a.x, threadIdx.x, scnt);
  int bid = blockIdx.x;
  if (bid < 1024) {                      // weights: 262144 threads
    int t = bid * 256 + threadIdx.x;
    int m    = t >> 15;
    int rem  = t & 32767;
    int tile = rem >> 6;
    int lane = rem & 63;
    int kb = tile >> 5, rt = tile & 31;
    int row = rt * 16 + (lane & 15);
    int k   = kb * 32 + (lane >> 4) * 8;
    u16 tmp[8];
    if (isbf) {
      const u16* s = (const u16*)a.src[m] + row * 512 + k;
#pragma unroll
      for (int j = 0; j < 8; j++) tmp[j] = s[j];
    } else {
      const float* s = (const float*)a.src[m] + row * 512 + k;
#pragma unroll
      for (int j = 0; j < 8; j++) tmp[j] = f2bf(s[j]);
    }
    uint4* d = (uint4*)(a.dst + (size_t)m * MAT_ELEMS + (size_t)tile * 512 + lane * 8);
    *d = *(const uint4*)tmp;
  } else {                               // ub blocks: 16384 threads
    int t = (bid - 1024) * 256 + threadIdx.x;
    if (t >= 8 * 32 * 64) return;
    int g    = t >> 11;
    int rem  = t & 2047;
    int tile = rem >> 6;
    int lane = rem & 63;
    int row = tile * 16 + (lane & 15);
    int kq  = (lane >> 4) * 8;
    u16 tmp[8];
#pragma unroll
    for (int j = 0; j < 8; j++) {
      int k = kq + j;
      float v = (k < 3) ? ldv(a.u[g], row * 3 + k, isbf)
              : (k == 3) ? ldv(a.bv[g], row, isbf) : 0.0f;
      tmp[j] = f2bf(v);
    }
    uint4* d = (uint4*)(a.dst + UB_OFF + (size_t)g * UB_ELEMS + (size_t)tile * 512 + lane * 8);
    *d = *(const uint4*)tmp;
  }
}

// ---------------- fused network kernel ----------------
struct KArgs {
  const void* x;  const void* W1; const void* b1;
  const void* Wout; const void* bout;
  const u16* ws;      // swizzled weights + ub blocks (bf16)
  void* out;
};

// Single-gate GEMM: acc = [U|b]@[x;1] + W@B over K=512, 64 rows/wave, N=64.
__device__ __forceinline__ void gemm_one(f32x4 acc[4][4],
    const u16* __restrict__ wmat, const u16* __restrict__ ubm,
    const u16* ldsB, const u16* xbuf, int wave, int lane, int l15, int quad)
{
#pragma unroll
  for (int rt = 0; rt < 4; rt++)
#pragma unroll
    for (int ct = 0; ct < 4; ct++)
      acc[rt][ct] = (f32x4){0.f, 0.f, 0.f, 0.f};
  {
    const u16* aub = ubm + (wave * 4) * 512 + lane * 8;
    bf16x8 a[4], b[4];
#pragma unroll
    for (int i = 0; i < 4; i++) a[i] = *(const bf16x8*)(aub + i * 512);
#pragma unroll
    for (int i = 0; i < 4; i++) b[i] = *(const bf16x8*)(xbuf + (i * 16 + l15) * 32 + quad * 8);
#pragma unroll
    for (int rt = 0; rt < 4; rt++)
#pragma unroll
      for (int ct = 0; ct < 4; ct++)
        acc[rt][ct] = __builtin_amdgcn_mfma_f32_16x16x32_bf16(a[rt], b[ct], acc[rt][ct], 0, 0, 0);
  }
  const u16* abase = wmat + (size_t)(wave * 4) * 512 + lane * 8;
  const u16* bbase = ldsB + l15 * PADC + quad * 8;
#pragma unroll
  for (int kb = 0; kb < 16; kb++) {
    bf16x8 a[4], b[4];
#pragma unroll
    for (int i = 0; i < 4; i++)
      a[i] = *(const bf16x8*)(abase + (size_t)kb * 16384 + i * 512);
#pragma unroll
    for (int i = 0; i < 4; i++)
      b[i] = *(const bf16x8*)(bbase + kb * 32 + i * 16 * PADC);
#pragma unroll
    for (int rt = 0; rt < 4; rt++)
#pragma unroll
      for (int ct = 0; ct < 4; ct++)
        acc[rt][ct] = __builtin_amdgcn_mfma_f32_16x16x32_bf16(a[rt], b[ct], acc[rt][ct], 0, 0, 0);
  }
}

__device__ __forceinline__ void pack_tanh(u32 dst[4][4][2], const f32x4 acc[4][4]) {
#pragma unroll
  for (int rt = 0; rt < 4; rt++)
#pragma unroll
    for (int ct = 0; ct < 4; ct++) {
      u16 t0 = f2bf(tanh_fast(acc[rt][ct][0]));
      u16 t1 = f2bf(tanh_fast(acc[rt][ct][1]));
      u16 t2 = f2bf(tanh_fast(acc[rt][ct][2]));
      u16 t3 = f2bf(tanh_fast(acc[rt][ct][3]));
      dst[rt][ct][0] = (u32)t0 | ((u32)t1 << 16);
      dst[rt][ct][1] = (u32)t2 | ((u32)t3 << 16);
    }
}

// min-waves-per-EU = 1: allow up to 512 regs/wave so the ~200-reg working set
// (64 AGPR acc + ~150 arch VGPR) allocates WITHOUT scratch spills. True
// occupancy stays 2 waves/SIMD (register-bound), same as before — we are
// removing the 250-400 MB/dispatch of scratch traffic, not buying occupancy.
__global__ __launch_bounds__(512, 1) void pdenet_kernel(KArgs ka) {
  __shared__ __align__(16) u16 ldsS[NT * PADC];   // S (intact within a layer)
  __shared__ __align__(16) u16 ldsR[NT * PADC];   // SR buffer
  __shared__ __align__(16) u16 xbuf[NT * 32];     // [x;1;0..] K=32 tile, col-major
  __shared__ int scnt[4];

  const int tid  = threadIdx.x;
  const int isbf = sniff_isbf(ka.x, tid, scnt);
  const int wave = tid >> 6;
  const int lane = tid & 63;
  const int l15  = lane & 15;
  const int quad = lane >> 4;
  const int c0   = blockIdx.x * NT;

  // build xbuf once
  for (int e = tid; e < NT * 32; e += 512) {
    int cc = e >> 5, k = e & 31;
    float v = (k < 3) ? ldv(ka.x, k * NCOL + c0 + cc, isbf)
            : (k == 3) ? 1.0f : 0.0f;
    xbuf[cc * 32 + k] = f2bf(v);
  }
  __syncthreads();

  // S1 = tanh(W1@x + b1): thread = row
  {
    int r = tid;
    float w0 = ldv(ka.W1, r * 3 + 0, isbf);
    float w1 = ldv(ka.W1, r * 3 + 1, isbf);
    float w2 = ldv(ka.W1, r * 3 + 2, isbf);
    float bb = ldv(ka.b1, r, isbf);
#pragma unroll 4
    for (int c = 0; c < NT; c++) {
      float x0 = bf2f(xbuf[c * 32 + 0]);
      float x1 = bf2f(xbuf[c * 32 + 1]);
      float x2 = bf2f(xbuf[c * 32 + 2]);
      float s = tanh_fast(w0 * x0 + w1 * x1 + w2 * x2 + bb);
      ldsS[c * PADC + r] = f2bf(s);
    }
  }
  __syncthreads();

  u32 zpk[4][4][2], gpk[4][4][2];

#pragma unroll 1
  for (int layer = 0; layer < 2; layer++) {
    const int g0 = layer * 4;
    const u16* ubb = ka.ws + UB_OFF;

    // ---- Z ----
    {
      f32x4 acc[4][4];
      gemm_one(acc, ka.ws + (size_t)(g0 + 0) * MAT_ELEMS,
               ubb + (size_t)(g0 + 0) * UB_ELEMS, ldsS, xbuf, wave, lane, l15, quad);
      pack_tanh(zpk, acc);
    }
    // ---- G ----
    {
      f32x4 acc[4][4];
      gemm_one(acc, ka.ws + (size_t)(g0 + 1) * MAT_ELEMS,
               ubb + (size_t)(g0 + 1) * UB_ELEMS, ldsS, xbuf, wave, lane, l15, quad);
      pack_tanh(gpk, acc);
    }
    // ---- R; SR = S * tanh(R) -> ldsR ----
    {
      f32x4 racc[4][4];
      gemm_one(racc, ka.ws + (size_t)(g0 + 2) * MAT_ELEMS,
               ubb + (size_t)(g0 + 2) * UB_ELEMS, ldsS, xbuf, wave, lane, l15, quad);
#pragma unroll
      for (int rt = 0; rt < 4; rt++)
#pragma unroll
        for (int ct = 0; ct < 4; ct++) {
          int c  = ct * 16 + l15;
          int rb = wave * 64 + rt * 16 + quad * 4;
          uint2 sv = *(const uint2*)&ldsS[c * PADC + rb];
          float s0 = bf2f((u16)(sv.x & 0xffffu)), s1 = bf2f((u16)(sv.x >> 16));
          float s2 = bf2f((u16)(sv.y & 0xffffu)), s3 = bf2f((u16)(sv.y >> 16));
          u16 o0 = f2bf(s0 * tanh_fast(racc[rt][ct][0]));
          u16 o1 = f2bf(s1 * tanh_fast(racc[rt][ct][1]));
          u16 o2 = f2bf(s2 * tanh_fast(racc[rt][ct][2]));
          u16 o3 = f2bf(s3 * tanh_fast(racc[rt][ct][3]));
          uint2 ov = { (u32)o0 | ((u32)o1 << 16), (u32)o2 | ((u32)o3 << 16) };
          *(uint2*)&ldsR[c * PADC + rb] = ov;
        }
    }
    __syncthreads();   // SR published

    // ---- H (B = ldsR); S_next = (1-G)*H + Z*S -> ldsS (own rows only) ----
    {
      f32x4 acc[4][4];
      gemm_one(acc, ka.ws + (size_t)(g0 + 3) * MAT_ELEMS,
               ubb + (size_t)(g0 + 3) * UB_ELEMS, ldsR, xbuf, wave, lane, l15, quad);
#pragma unroll
      for (int rt = 0; rt < 4; rt++)
#pragma unroll
        for (int ct = 0; ct < 4; ct++) {
          int c  = ct * 16 + l15;
          int rb = wave * 64 + rt * 16 + quad * 4;
          uint2 sv = *(const uint2*)&ldsS[c * PADC + rb];
          u16 o[4];
#pragma unroll
          for (int i = 0; i < 4; i++) {
            float h = tanh_fast(acc[rt][ct][i]);
            u32 zp = zpk[rt][ct][i >> 1], gp = gpk[rt][ct][i >> 1];
            u32 sp = (i >> 1) ? sv.y : sv.x;
            float z = bf2f((u16)((i & 1) ? (zp >> 16) : (zp & 0xffffu)));
            float g = bf2f((u16)((i & 1) ? (gp >> 16) : (gp & 0xffffu)));
            float s = bf2f((u16)((i & 1) ? (sp >> 16) : (sp & 0xffffu)));
            o[i] = f2bf((1.0f - g) * h + z * s);
          }
          uint2 ov = { (u32)o[0] | ((u32)o[1] << 16), (u32)o[2] | ((u32)o[3] << 16) };
          *(uint2*)&ldsS[c * PADC + rb] = ov;
        }
    }
    __syncthreads();   // S_next published
  }

  // ---- out = W @ S3 + b : 8 threads/col ----
  {
    int c = tid >> 3;
    int seg = tid & 7;
    float p = 0.0f;
#pragma unroll
    for (int t = 0; t < 8; t++) {
      int rbase = t * 64 + seg * 8;
      bf16x8 s8 = *(const bf16x8*)&ldsS[c * PADC + rbase];
#pragma unroll
      for (int j = 0; j < 8; j++)
        p += ldv(ka.Wout, rbase + j, isbf) * bf2f((u16)s8[j]);
    }
    p += __shfl_xor(p, 1);
    p += __shfl_xor(p, 2);
    p += __shfl_xor(p, 4);
    if (seg == 0) {
      float res = p + ldv(ka.bout, 0, isbf);
      if (isbf) ((u16*)ka.out)[c0 + c] = f2bf(res);
      else      ((float*)ka.out)[c0 + c] = res;
    }
  }
}

extern "C" void kernel_launch(void* const* d_in, const int* in_sizes, int n_in,
                              void* d_out, int out_size, void* d_ws, size_t ws_size,
                              hipStream_t stream) {
  // 0:x 1:W1 2:b1 | 3:Uz1 4:Wz1 5:bz1 | 6:Ug1 7:Wg1 8:bg1 | 9:Ur1 10:Wr1 11:br1
  // 12:Uh1 13:Wh1 14:bh1 | 15:Uz2 16:Wz2 17:bz2 | 18:Ug2 19:Wg2 20:bg2
  // 21:Ur2 22:Wr2 23:br2 | 24:Uh2 25:Wh2 26:bh2 | 27:W 28:b
  static const int widx[8] = {4, 7, 10, 13, 16, 19, 22, 25};
  static const int uidx[8] = {3, 6, 9, 12, 15, 18, 21, 24};
  static const int bidx[8] = {5, 8, 11, 14, 17, 20, 23, 26};

  u16* ws16 = (u16*)d_ws;

  SwzArgs sa;
  for (int i = 0; i < 8; i++) {
    sa.src[i] = d_in[widx[i]];
    sa.u[i]   = d_in[uidx[i]];
    sa.bv[i]  = d_in[bidx[i]];
  }
  sa.x   = d_in[0];
  sa.dst = ws16;
  hipLaunchKernelGGL(swizzle_kernel, dim3(1024 + 64), dim3(256), 0, stream, sa);

  KArgs ka;
  ka.x    = d_in[0];
  ka.W1   = d_in[1];
  ka.b1   = d_in[2];
  ka.Wout = d_in[27];
  ka.bout = d_in[28];
  ka.ws   = ws16;
  ka.out  = d_out;
  hipLaunchKernelGGL(pdenet_kernel, dim3(NCOL / NT), dim3(512), 0, stream, ka);
}

// Round 6
// 688.391 us; speedup vs baseline: 4.4319x; 1.3528x over previous
//
#include <hip/hip_runtime.h>

typedef unsigned short u16;
typedef unsigned int   u32;
typedef short bf16x8 __attribute__((ext_vector_type(8)));
typedef float f32x4  __attribute__((ext_vector_type(4)));

#define HID   512
#define NT    64            // columns per workgroup
#define NCOL  65536
#define PADC  520           // LDS column stride (elements)
#define MAT_ELEMS (512 * 512)
#define UB_ELEMS  (512 * 32)                 // per-gate [U|b|0..] block, swizzled
#define UB_OFF    (8 * MAT_ELEMS)            // u16 offset of ub blocks in ws

__device__ __forceinline__ float bf2f(u16 v) {
  union { u32 u; float f; } t; t.u = ((u32)v) << 16; return t.f;
}
__device__ __forceinline__ u16 f2bf(float f) {
  union { float f; u32 u; } t; t.f = f;
  u32 r = t.u + 0x7fffu + ((t.u >> 16) & 1u);   // round-to-nearest-even
  return (u16)(r >> 16);
}
__device__ __forceinline__ float ldv(const void* p, int i, int isbf) {
  return isbf ? bf2f(((const u16*)p)[i]) : ((const float*)p)[i];
}
__device__ __forceinline__ float tanh_fast(float x) {
  float e = __builtin_amdgcn_exp2f(x * 2.8853900817779268f); // 2*log2(e)
  return 1.0f - 2.0f * __builtin_amdgcn_rcpf(e + 1.0f);
}

// block-uniform dtype sniff: first 256 threads inspect x's first 256 u16s.
__device__ __forceinline__ int sniff_isbf(const void* x, int tid, int* scnt) {
  if (tid < 256) {
    u32 e = (((const u16*)x)[tid] >> 7) & 0xFFu;
    int ok = (e == 0u || (e - 100u) <= 40u) ? 1 : 0;
    unsigned long long m = __ballot(ok);
    if ((tid & 63) == 0) scnt[tid >> 6] = __popcll(m);
  }
  __syncthreads();
  return ((scnt[0] + scnt[1] + scnt[2] + scnt[3]) >= 220) ? 1 : 0;
}

// ---------------- weight swizzle pre-pass ----------------
// Weight tile = kb*32 + rt, 512 bf16/tile, element (lane,j) at tile*512+lane*8+j,
// row = rt*16 + (lane&15), k = kb*32 + (lane>>4)*8 + j.
// ub block per gate: tile = rt (32 tiles), same lane layout, k' = (lane>>4)*8+j:
//   k'<3 -> U[row][k'], k'==3 -> bias[row], else 0.
struct SwzArgs {
  const void* src[8]; const void* u[8]; const void* bv[8];
  const void* x; u16* dst;
};

__global__ void swizzle_kernel(SwzArgs a) {
  __shared__ int scnt[4];
  const int isbf = sniff_isbf(a.x, threadIdx.x, scnt);
  int bid = blockIdx.x;
  if (bid < 1024) {                      // weights: 262144 threads
    int t = bid * 256 + threadIdx.x;
    int m    = t >> 15;
    int rem  = t & 32767;
    int tile = rem >> 6;
    int lane = rem & 63;
    int kb = tile >> 5, rt = tile & 31;
    int row = rt * 16 + (lane & 15);
    int k   = kb * 32 + (lane >> 4) * 8;
    u16 tmp[8];
    if (isbf) {
      const u16* s = (const u16*)a.src[m] + row * 512 + k;
#pragma unroll
      for (int j = 0; j < 8; j++) tmp[j] = s[j];
    } else {
      const float* s = (const float*)a.src[m] + row * 512 + k;
#pragma unroll
      for (int j = 0; j < 8; j++) tmp[j] = f2bf(s[j]);
    }
    uint4* d = (uint4*)(a.dst + (size_t)m * MAT_ELEMS + (size_t)tile * 512 + lane * 8);
    *d = *(const uint4*)tmp;
  } else {                               // ub blocks: 16384 threads
    int t = (bid - 1024) * 256 + threadIdx.x;
    if (t >= 8 * 32 * 64) return;
    int g    = t >> 11;
    int rem  = t & 2047;
    int tile = rem >> 6;
    int lane = rem & 63;
    int row = tile * 16 + (lane & 15);
    int kq  = (lane >> 4) * 8;
    u16 tmp[8];
#pragma unroll
    for (int j = 0; j < 8; j++) {
      int k = kq + j;
      float v = (k < 3) ? ldv(a.u[g], row * 3 + k, isbf)
              : (k == 3) ? ldv(a.bv[g], row, isbf) : 0.0f;
      tmp[j] = f2bf(v);
    }
    uint4* d = (uint4*)(a.dst + UB_OFF + (size_t)g * UB_ELEMS + (size_t)tile * 512 + lane * 8);
    *d = *(const uint4*)tmp;
  }
}

// ---------------- fused network kernel ----------------
struct KArgs {
  const void* x;  const void* W1; const void* b1;
  const void* Wout; const void* bout;
  const u16* ws;      // swizzled weights + ub blocks (bf16)
  void* out;
};

// Gate GEMM as a unified 17-step K-loop (step 0 = [U|b]@[x;1], steps 1..16 =
// W@B kb-blocks) with 1-deep A prefetch (a[2][4] rolling buffer).
__device__ __forceinline__ void gemm_one(f32x4 acc[4][4],
    const u16* __restrict__ wmat, const u16* __restrict__ ubm,
    const u16* ldsB, const u16* xbuf, int wave, int lane, int l15, int quad)
{
  const u16* aub   = ubm  + (wave * 4) * 512 + lane * 8;
  const u16* abase = wmat + (size_t)(wave * 4) * 512 + lane * 8;
  const u16* bbase = ldsB + l15 * PADC + quad * 8;

#pragma unroll
  for (int rt = 0; rt < 4; rt++)
#pragma unroll
    for (int ct = 0; ct < 4; ct++)
      acc[rt][ct] = (f32x4){0.f, 0.f, 0.f, 0.f};

  bf16x8 a[2][4];
#pragma unroll
  for (int i = 0; i < 4; i++) a[0][i] = *(const bf16x8*)(aub + i * 512);

#pragma unroll
  for (int s = 0; s < 17; s++) {
    if (s < 16) {
#pragma unroll
      for (int i = 0; i < 4; i++)
        a[(s + 1) & 1][i] = *(const bf16x8*)(abase + (size_t)s * 16384 + i * 512);
    }
    bf16x8 b[4];
    if (s == 0) {
#pragma unroll
      for (int i = 0; i < 4; i++)
        b[i] = *(const bf16x8*)(xbuf + (i * 16 + l15) * 32 + quad * 8);
    } else {
#pragma unroll
      for (int i = 0; i < 4; i++)
        b[i] = *(const bf16x8*)(bbase + (s - 1) * 32 + i * 16 * PADC);
    }
#pragma unroll
    for (int rt = 0; rt < 4; rt++)
#pragma unroll
      for (int ct = 0; ct < 4; ct++)
        acc[rt][ct] = __builtin_amdgcn_mfma_f32_16x16x32_bf16(a[s & 1][rt], b[ct], acc[rt][ct], 0, 0, 0);
  }
}

// Gate order per layer: R -> H -> Z -> G. H is parked in LDS (overwrites SR in
// ldsR after a barrier) so the only gate state held in VGPRs across a gemm is
// z (32 packed regs, during the G gemm). This keeps arch VGPRs <= 128 so the
// allocator (which pins 128 to hold 2 waves/SIMD) does not spill to scratch —
// R2-R5 showed 268-345 MB/dispatch of scratch traffic <-> duration.
__global__ __launch_bounds__(512, 1) void pdenet_kernel(KArgs ka) {
  __shared__ __align__(16) u16 ldsS[NT * PADC];   // S (intact within a layer)
  __shared__ __align__(16) u16 ldsR[NT * PADC];   // SR, then packed H
  __shared__ __align__(16) u16 xbuf[NT * 32];     // [x;1;0..] K=32 tile, col-major
  __shared__ int scnt[4];

  const int tid  = threadIdx.x;
  const int isbf = sniff_isbf(ka.x, tid, scnt);
  const int wave = tid >> 6;
  const int lane = tid & 63;
  const int l15  = lane & 15;
  const int quad = lane >> 4;
  const int c0   = blockIdx.x * NT;

  // build xbuf once
  for (int e = tid; e < NT * 32; e += 512) {
    int cc = e >> 5, k = e & 31;
    float v = (k < 3) ? ldv(ka.x, k * NCOL + c0 + cc, isbf)
            : (k == 3) ? 1.0f : 0.0f;
    xbuf[cc * 32 + k] = f2bf(v);
  }
  __syncthreads();

  // S1 = tanh(W1@x + b1): thread = row
  {
    int r = tid;
    float w0 = ldv(ka.W1, r * 3 + 0, isbf);
    float w1 = ldv(ka.W1, r * 3 + 1, isbf);
    float w2 = ldv(ka.W1, r * 3 + 2, isbf);
    float bb = ldv(ka.b1, r, isbf);
#pragma unroll 4
    for (int c = 0; c < NT; c++) {
      float x0 = bf2f(xbuf[c * 32 + 0]);
      float x1 = bf2f(xbuf[c * 32 + 1]);
      float x2 = bf2f(xbuf[c * 32 + 2]);
      float s = tanh_fast(w0 * x0 + w1 * x1 + w2 * x2 + bb);
      ldsS[c * PADC + r] = f2bf(s);
    }
  }
  __syncthreads();

#pragma unroll 1
  for (int layer = 0; layer < 2; layer++) {
    const int g0 = layer * 4;
    const u16* ubb = ka.ws + UB_OFF;

    // ---- R (gate idx 2); SR = S * tanh(R) -> ldsR ----
    {
      f32x4 racc[4][4];
      gemm_one(racc, ka.ws + (size_t)(g0 + 2) * MAT_ELEMS,
               ubb + (size_t)(g0 + 2) * UB_ELEMS, ldsS, xbuf, wave, lane, l15, quad);
#pragma unroll
      for (int rt = 0; rt < 4; rt++)
#pragma unroll
        for (int ct = 0; ct < 4; ct++) {
          int c  = ct * 16 + l15;
          int rb = wave * 64 + rt * 16 + quad * 4;
          uint2 sv = *(const uint2*)&ldsS[c * PADC + rb];
          float s0 = bf2f((u16)(sv.x & 0xffffu)), s1 = bf2f((u16)(sv.x >> 16));
          float s2 = bf2f((u16)(sv.y & 0xffffu)), s3 = bf2f((u16)(sv.y >> 16));
          u16 o0 = f2bf(s0 * tanh_fast(racc[rt][ct][0]));
          u16 o1 = f2bf(s1 * tanh_fast(racc[rt][ct][1]));
          u16 o2 = f2bf(s2 * tanh_fast(racc[rt][ct][2]));
          u16 o3 = f2bf(s3 * tanh_fast(racc[rt][ct][3]));
          uint2 ov = { (u32)o0 | ((u32)o1 << 16), (u32)o2 | ((u32)o3 << 16) };
          *(uint2*)&ldsR[c * PADC + rb] = ov;
        }
    }
    __syncthreads();   // SR published

    // ---- H (gate idx 3, B = ldsR); then park tanh(H) in ldsR ----
    {
      f32x4 hacc[4][4];
      gemm_one(hacc, ka.ws + (size_t)(g0 + 3) * MAT_ELEMS,
               ubb + (size_t)(g0 + 3) * UB_ELEMS, ldsR, xbuf, wave, lane, l15, quad);
      __syncthreads();   // all waves done reading SR; safe to overwrite
#pragma unroll
      for (int rt = 0; rt < 4; rt++)
#pragma unroll
        for (int ct = 0; ct < 4; ct++) {
          int c  = ct * 16 + l15;
          int rb = wave * 64 + rt * 16 + quad * 4;
          u16 h0 = f2bf(tanh_fast(hacc[rt][ct][0]));
          u16 h1 = f2bf(tanh_fast(hacc[rt][ct][1]));
          u16 h2 = f2bf(tanh_fast(hacc[rt][ct][2]));
          u16 h3 = f2bf(tanh_fast(hacc[rt][ct][3]));
          uint2 hv = { (u32)h0 | ((u32)h1 << 16), (u32)h2 | ((u32)h3 << 16) };
          *(uint2*)&ldsR[c * PADC + rb] = hv;   // own rows; read back by same wave
        }
    }

    // ---- Z (gate idx 0) -> packed regs ----
    u32 zpk[4][4][2];
    {
      f32x4 zacc[4][4];
      gemm_one(zacc, ka.ws + (size_t)(g0 + 0) * MAT_ELEMS,
               ubb + (size_t)(g0 + 0) * UB_ELEMS, ldsS, xbuf, wave, lane, l15, quad);
#pragma unroll
      for (int rt = 0; rt < 4; rt++)
#pragma unroll
        for (int ct = 0; ct < 4; ct++) {
          u16 t0 = f2bf(tanh_fast(zacc[rt][ct][0]));
          u16 t1 = f2bf(tanh_fast(zacc[rt][ct][1]));
          u16 t2 = f2bf(tanh_fast(zacc[rt][ct][2]));
          u16 t3 = f2bf(tanh_fast(zacc[rt][ct][3]));
          zpk[rt][ct][0] = (u32)t0 | ((u32)t1 << 16);
          zpk[rt][ct][1] = (u32)t2 | ((u32)t3 << 16);
        }
    }

    // ---- G (gate idx 1); S_next = (1-G)*H + Z*S -> ldsS ----
    {
      f32x4 gacc[4][4];
      gemm_one(gacc, ka.ws + (size_t)(g0 + 1) * MAT_ELEMS,
               ubb + (size_t)(g0 + 1) * UB_ELEMS, ldsS, xbuf, wave, lane, l15, quad);
      __syncthreads();   // all waves done reading S as B operand
#pragma unroll
      for (int rt = 0; rt < 4; rt++)
#pragma unroll
        for (int ct = 0; ct < 4; ct++) {
          int c  = ct * 16 + l15;
          int rb = wave * 64 + rt * 16 + quad * 4;
          uint2 sv = *(const uint2*)&ldsS[c * PADC + rb];
          uint2 hv = *(const uint2*)&ldsR[c * PADC + rb];
          u16 o[4];
#pragma unroll
          for (int i = 0; i < 4; i++) {
            float g = tanh_fast(gacc[rt][ct][i]);
            u32 zp = zpk[rt][ct][i >> 1];
            u32 sp = (i >> 1) ? sv.y : sv.x;
            u32 hp = (i >> 1) ? hv.y : hv.x;
            float z = bf2f((u16)((i & 1) ? (zp >> 16) : (zp & 0xffffu)));
            float s = bf2f((u16)((i & 1) ? (sp >> 16) : (sp & 0xffffu)));
            float h = bf2f((u16)((i & 1) ? (hp >> 16) : (hp & 0xffffu)));
            o[i] = f2bf((1.0f - g) * h + z * s);
          }
          uint2 ov = { (u32)o[0] | ((u32)o[1] << 16), (u32)o[2] | ((u32)o[3] << 16) };
          *(uint2*)&ldsS[c * PADC + rb] = ov;
        }
    }
    __syncthreads();   // S_next published
  }

  // ---- out = W @ S3 + b : 8 threads/col ----
  {
    int c = tid >> 3;
    int seg = tid & 7;
    float p = 0.0f;
#pragma unroll
    for (int t = 0; t < 8; t++) {
      int rbase = t * 64 + seg * 8;
      bf16x8 s8 = *(const bf16x8*)&ldsS[c * PADC + rbase];
#pragma unroll
      for (int j = 0; j < 8; j++)
        p += ldv(ka.Wout, rbase + j, isbf) * bf2f((u16)s8[j]);
    }
    p += __shfl_xor(p, 1);
    p += __shfl_xor(p, 2);
    p += __shfl_xor(p, 4);
    if (seg == 0) {
      float res = p + ldv(ka.bout, 0, isbf);
      if (isbf) ((u16*)ka.out)[c0 + c] = f2bf(res);
      else      ((float*)ka.out)[c0 + c] = res;
    }
  }
}

extern "C" void kernel_launch(void* const* d_in, const int* in_sizes, int n_in,
                              void* d_out, int out_size, void* d_ws, size_t ws_size,
                              hipStream_t stream) {
  // 0:x 1:W1 2:b1 | 3:Uz1 4:Wz1 5:bz1 | 6:Ug1 7:Wg1 8:bg1 | 9:Ur1 10:Wr1 11:br1
  // 12:Uh1 13:Wh1 14:bh1 | 15:Uz2 16:Wz2 17:bz2 | 18:Ug2 19:Wg2 20:bg2
  // 21:Ur2 22:Wr2 23:br2 | 24:Uh2 25:Wh2 26:bh2 | 27:W 28:b
  static const int widx[8] = {4, 7, 10, 13, 16, 19, 22, 25};
  static const int uidx[8] = {3, 6, 9, 12, 15, 18, 21, 24};
  static const int bidx[8] = {5, 8, 11, 14, 17, 20, 23, 26};

  u16* ws16 = (u16*)d_ws;

  SwzArgs sa;
  for (int i = 0; i < 8; i++) {
    sa.src[i] = d_in[widx[i]];
    sa.u[i]   = d_in[uidx[i]];
    sa.bv[i]  = d_in[bidx[i]];
  }
  sa.x   = d_in[0];
  sa.dst = ws16;
  hipLaunchKernelGGL(swizzle_kernel, dim3(1024 + 64), dim3(256), 0, stream, sa);

  KArgs ka;
  ka.x    = d_in[0];
  ka.W1   = d_in[1];
  ka.b1   = d_in[2];
  ka.Wout = d_in[27];
  ka.bout = d_in[28];
  ka.ws   = ws16;
  ka.out  = d_out;
  hipLaunchKernelGGL(pdenet_kernel, dim3(NCOL / NT), dim3(512), 0, stream, ka);
}